// Round 1
// baseline (1327.239 us; speedup 1.0000x reference)
//
#include <hip/hip_runtime.h>
#include <math.h>

#define D 256        // embedding dim
#define P 128        // projection dim
#define K 8192       // num embeddings
#define NTOK 16384   // 16*1024 tokens
#define NROWS (NTOK + K)
#define NCHUNK 8
#define KCHUNK (K / NCHUNK)   // 1024
#define TPB_TOK 64
#define TILE_K 64
#define FLT_BIG 3.402823466e+38f

// ---------------------------------------------------------------------------
// Kernel 1: zero-fill the one-hot output region (512 MB) with float4 stores.
// ---------------------------------------------------------------------------
__global__ __launch_bounds__(256) void zero_kernel(float4* __restrict__ p, size_t n4) {
    size_t i = (size_t)blockIdx.x * blockDim.x + threadIdx.x;
    size_t stride = (size_t)gridDim.x * blockDim.x;
    float4 z; z.x = 0.f; z.y = 0.f; z.z = 0.f; z.w = 0.f;
    for (; i < n4; i += stride) p[i] = z;
}

// ---------------------------------------------------------------------------
// Kernel 2: fused projection of x (rows < NTOK) and codebook (rows >= NTOK).
// out[r][p] = sum_d A[r][d] * w[d][p]  (+ b[p] afterwards, like the reference)
// Also emits row norms of the projected vectors.
// Block: 256 threads = 16 rows x 16 col-groups (8 cols each). Grid: NROWS/16.
// ---------------------------------------------------------------------------
__global__ __launch_bounds__(256) void proj_kernel(
    const float* __restrict__ x, const float* __restrict__ cb,
    const float* __restrict__ w, const float* __restrict__ bias,
    float* __restrict__ xproj, float* __restrict__ cproj,
    float* __restrict__ xnorm, float* __restrict__ cnorm)
{
    __shared__ float As[16][D];   // 16 KB
    const int tid = threadIdx.x;
    const int row0 = blockIdx.x * 16;

    // Stage 16 source rows (256 floats each) into LDS, coalesced float4.
    for (int i = tid; i < 16 * (D / 4); i += 256) {
        int r = i / (D / 4);
        int c4 = i % (D / 4);
        int gr = row0 + r;
        const float* src = (gr < NTOK) ? (x + (size_t)gr * D)
                                       : (cb + (size_t)(gr - NTOK) * D);
        float4 v = ((const float4*)src)[c4];
        ((float4*)&As[r][0])[c4] = v;
    }
    __syncthreads();

    const int r = tid >> 4;          // 0..15
    const int c0 = (tid & 15) * 8;   // 0..120

    float acc[8];
#pragma unroll
    for (int j = 0; j < 8; j++) acc[j] = 0.f;

    for (int d = 0; d < D; d += 4) {
        float4 a4 = *(const float4*)&As[r][d];
#pragma unroll
        for (int dd = 0; dd < 4; dd++) {
            float av = (dd == 0) ? a4.x : (dd == 1) ? a4.y : (dd == 2) ? a4.z : a4.w;
            float4 w0 = *(const float4*)&w[(size_t)(d + dd) * P + c0];
            float4 w1 = *(const float4*)&w[(size_t)(d + dd) * P + c0 + 4];
            acc[0] = fmaf(av, w0.x, acc[0]);
            acc[1] = fmaf(av, w0.y, acc[1]);
            acc[2] = fmaf(av, w0.z, acc[2]);
            acc[3] = fmaf(av, w0.w, acc[3]);
            acc[4] = fmaf(av, w1.x, acc[4]);
            acc[5] = fmaf(av, w1.y, acc[5]);
            acc[6] = fmaf(av, w1.z, acc[6]);
            acc[7] = fmaf(av, w1.w, acc[7]);
        }
    }

    // Add bias after the dot (matches reference "x @ w + b" rounding order).
    float out[8];
    float nrm = 0.f;
#pragma unroll
    for (int j = 0; j < 8; j++) {
        out[j] = acc[j] + bias[c0 + j];
        nrm = fmaf(out[j], out[j], nrm);
    }

    const int gr = row0 + r;
    float* dst = (gr < NTOK) ? (xproj + (size_t)gr * P)
                             : (cproj + (size_t)(gr - NTOK) * P);
    float4 o0; o0.x = out[0]; o0.y = out[1]; o0.z = out[2]; o0.w = out[3];
    float4 o1; o1.x = out[4]; o1.y = out[5]; o1.z = out[6]; o1.w = out[7];
    *(float4*)&dst[c0] = o0;
    *(float4*)&dst[c0 + 4] = o1;

    // Reduce norm across the 16 threads sharing this row (contiguous lanes).
#pragma unroll
    for (int off = 1; off < 16; off <<= 1)
        nrm += __shfl_xor(nrm, off, 16);
    if ((tid & 15) == 0) {
        if (gr < NTOK) xnorm[gr] = nrm;
        else           cnorm[gr - NTOK] = nrm;
    }
}

// ---------------------------------------------------------------------------
// Kernel 3: distance argmin, tiled. Block = 256 thr handles 64 tokens x a
// 1024-code chunk (blockIdx.y). Thread (ty,tx) accumulates a 4x4 dot tile.
// dist = (xnorm - 2*dot) + cnorm  (replicates reference rounding order).
// Tie-break: lowest code index (matches jnp.argmin first-occurrence).
// ---------------------------------------------------------------------------
__global__ __launch_bounds__(256) void argmin_kernel(
    const float* __restrict__ xproj, const float* __restrict__ cproj,
    const float* __restrict__ xnorm, const float* __restrict__ cnorm,
    float* __restrict__ pvals, int* __restrict__ pidx)
{
    __shared__ float xs[TPB_TOK][P + 4];   // 64 x 132 fp32 = 33 KB
    __shared__ float cs[TILE_K][P + 4];    // 33 KB
    __shared__ float rv[TPB_TOK][17];
    __shared__ int   ri[TPB_TOK][17];

    const int tid = threadIdx.x;
    const int tok0 = blockIdx.x * TPB_TOK;
    const int k0 = blockIdx.y * KCHUNK;
    const int ty = tid >> 4;   // 0..15
    const int tx = tid & 15;   // 0..15

    // Load the 64-token x_proj tile once.
    for (int i = tid; i < TPB_TOK * (P / 4); i += 256) {
        int t = i >> 5;
        int p4 = i & 31;
        float4 v = ((const float4*)(xproj + (size_t)(tok0 + t) * P))[p4];
        *(float4*)&xs[t][p4 * 4] = v;
    }

    float bestv[4];
    int besti[4];
    float xn[4];
#pragma unroll
    for (int i = 0; i < 4; i++) {
        bestv[i] = FLT_BIG;
        besti[i] = 0;
        xn[i] = xnorm[tok0 + ty * 4 + i];
    }

    for (int kt = 0; kt < KCHUNK; kt += TILE_K) {
        __syncthreads();   // previous tile fully consumed (also orders xs load)
        for (int i = tid; i < TILE_K * (P / 4); i += 256) {
            int c = i >> 5;
            int p4 = i & 31;
            float4 v = ((const float4*)(cproj + (size_t)(k0 + kt + c) * P))[p4];
            *(float4*)&cs[c][p4 * 4] = v;
        }
        __syncthreads();

        float acc[4][4];
#pragma unroll
        for (int i = 0; i < 4; i++)
#pragma unroll
            for (int j = 0; j < 4; j++) acc[i][j] = 0.f;

#pragma unroll 4
        for (int p = 0; p < P; p += 4) {
            float4 a0 = *(const float4*)&xs[ty * 4 + 0][p];
            float4 a1 = *(const float4*)&xs[ty * 4 + 1][p];
            float4 a2 = *(const float4*)&xs[ty * 4 + 2][p];
            float4 a3 = *(const float4*)&xs[ty * 4 + 3][p];
            float4 b0 = *(const float4*)&cs[tx * 4 + 0][p];
            float4 b1 = *(const float4*)&cs[tx * 4 + 1][p];
            float4 b2 = *(const float4*)&cs[tx * 4 + 2][p];
            float4 b3 = *(const float4*)&cs[tx * 4 + 3][p];
#pragma unroll
            for (int i = 0; i < 4; i++) {
                float4 a = (i == 0) ? a0 : (i == 1) ? a1 : (i == 2) ? a2 : a3;
#pragma unroll
                for (int j = 0; j < 4; j++) {
                    float4 b = (j == 0) ? b0 : (j == 1) ? b1 : (j == 2) ? b2 : b3;
                    float s = acc[i][j];
                    s = fmaf(a.x, b.x, s);
                    s = fmaf(a.y, b.y, s);
                    s = fmaf(a.z, b.z, s);
                    s = fmaf(a.w, b.w, s);
                    acc[i][j] = s;
                }
            }
        }

#pragma unroll
        for (int j = 0; j < 4; j++) {
            int k = k0 + kt + tx * 4 + j;
            float cn = cnorm[k];
#pragma unroll
            for (int i = 0; i < 4; i++) {
                float m2 = 2.0f * acc[i][j];
                float t = xn[i] - m2;
                float dist = t + cn;
                if (dist < bestv[i]) { bestv[i] = dist; besti[i] = k; }
            }
        }
    }

    // Block-level reduce across the 16 tx columns per token.
#pragma unroll
    for (int i = 0; i < 4; i++) {
        rv[ty * 4 + i][tx] = bestv[i];
        ri[ty * 4 + i][tx] = besti[i];
    }
    __syncthreads();
    if (tid < TPB_TOK) {
        float bv = rv[tid][0];
        int bi = ri[tid][0];
#pragma unroll
        for (int t = 1; t < 16; t++) {
            float v = rv[tid][t];
            int ix = ri[tid][t];
            if (v < bv || (v == bv && ix < bi)) { bv = v; bi = ix; }
        }
        size_t o = (size_t)(tok0 + tid) * NCHUNK + blockIdx.y;
        pvals[o] = bv;
        pidx[o] = bi;
    }
}

// ---------------------------------------------------------------------------
// Kernel 4: reduce chunk partials, write the one-hot 1.0, gather codebook row.
// Block = 256 threads handles 64 tokens. Grid: NTOK/64 = 256.
// ---------------------------------------------------------------------------
__global__ __launch_bounds__(256) void finalize_kernel(
    const float* __restrict__ pvals, const int* __restrict__ pidx,
    const float* __restrict__ cb,
    float* __restrict__ discrete, float* __restrict__ quant)
{
    __shared__ int sidx[64];
    const int tid = threadIdx.x;
    const int tok0 = blockIdx.x * 64;

    if (tid < 64) {
        int t = tok0 + tid;
        const float* pv = pvals + (size_t)t * NCHUNK;
        const int* pi = pidx + (size_t)t * NCHUNK;
        float bv = pv[0];
        int bi = pi[0];
#pragma unroll
        for (int c = 1; c < NCHUNK; c++) {
            float v = pv[c];
            int ix = pi[c];
            if (v < bv || (v == bv && ix < bi)) { bv = v; bi = ix; }
        }
        sidx[tid] = bi;
        discrete[(size_t)t * K + bi] = 1.0f;
    }
    __syncthreads();

    // Gather codebook rows: 64 tokens x 64 float4 per row.
    for (int i = tid; i < 64 * (D / 4); i += 256) {
        int t = i >> 6;
        int c4 = i & 63;
        int bi = sidx[t];
        float4 v = ((const float4*)(cb + (size_t)bi * D))[c4];
        ((float4*)(quant + (size_t)(tok0 + t) * D))[c4] = v;
    }
}

// ---------------------------------------------------------------------------
extern "C" void kernel_launch(void* const* d_in, const int* in_sizes, int n_in,
                              void* d_out, int out_size, void* d_ws, size_t ws_size,
                              hipStream_t stream) {
    const float* x    = (const float*)d_in[0];   // [16,1024,256]
    const float* cb   = (const float*)d_in[1];   // [8192,256]
    const float* w    = (const float*)d_in[2];   // [256,128]
    const float* bias = (const float*)d_in[3];   // [128]

    float* out = (float*)d_out;
    float* discrete = out;                               // [16384, 8192]
    float* quant = out + (size_t)NTOK * K;               // [16384, 256]

    float* ws = (float*)d_ws;
    float* xproj = ws;                                   // NTOK*P
    float* cproj = xproj + (size_t)NTOK * P;             // K*P
    float* xnorm = cproj + (size_t)K * P;                // NTOK
    float* cnorm = xnorm + NTOK;                         // K
    float* pvals = cnorm + K;                            // NTOK*NCHUNK
    int*   pidx  = (int*)(pvals + (size_t)NTOK * NCHUNK);

    zero_kernel<<<dim3(8192), dim3(256), 0, stream>>>(
        (float4*)discrete, (size_t)NTOK * K / 4);

    proj_kernel<<<dim3(NROWS / 16), dim3(256), 0, stream>>>(
        x, cb, w, bias, xproj, cproj, xnorm, cnorm);

    argmin_kernel<<<dim3(NTOK / TPB_TOK, NCHUNK), dim3(256), 0, stream>>>(
        xproj, cproj, xnorm, cnorm, pvals, pidx);

    finalize_kernel<<<dim3(NTOK / 64), dim3(256), 0, stream>>>(
        pvals, pidx, cb, discrete, quant);
}

// Round 3
// 996.483 us; speedup vs baseline: 1.3319x; 1.3319x over previous
//
#include <hip/hip_runtime.h>
#include <math.h>

#define D 256        // embedding dim
#define P 128        // projection dim
#define K 8192       // num embeddings
#define NTOK 16384   // 16*1024 tokens
#define NROWS (NTOK + K)
#define NCHUNK 8
#define KCHUNK (K / NCHUNK)   // 1024 codes per chunk
#define CAP 15               // candidate slots per (token, chunk); record = 16 ints
#define MARGIN 3.0f
#define FLT_BIG 3.402823466e+38f

typedef __attribute__((ext_vector_type(8))) short bf16x8;
typedef __attribute__((ext_vector_type(4))) float f32x4;
typedef __attribute__((ext_vector_type(8))) unsigned short u16x8;

__device__ __forceinline__ unsigned short f32_to_bf16_rne(float f) {
    unsigned int u = __float_as_uint(f);
    u = (u + 0x7fffu + ((u >> 16) & 1u)) >> 16;
    return (unsigned short)u;
}

// ---------------------------------------------------------------------------
// Kernel 1: fused projection of x (rows < NTOK) and codebook (rows >= NTOK).
// Emits fp32 projections + row norms + bf16 copies for the MFMA filter.
// ---------------------------------------------------------------------------
__global__ __launch_bounds__(256) void proj_kernel(
    const float* __restrict__ x, const float* __restrict__ cb,
    const float* __restrict__ w, const float* __restrict__ bias,
    float* __restrict__ xproj, float* __restrict__ cproj,
    float* __restrict__ xnorm, float* __restrict__ cnorm,
    unsigned short* __restrict__ xh, unsigned short* __restrict__ ch)
{
    __shared__ float As[16][D];   // 16 KB
    const int tid = threadIdx.x;
    const int row0 = blockIdx.x * 16;

    for (int i = tid; i < 16 * (D / 4); i += 256) {
        int r = i / (D / 4);
        int c4 = i % (D / 4);
        int gr = row0 + r;
        const float* src = (gr < NTOK) ? (x + (size_t)gr * D)
                                       : (cb + (size_t)(gr - NTOK) * D);
        float4 v = ((const float4*)src)[c4];
        ((float4*)&As[r][0])[c4] = v;
    }
    __syncthreads();

    const int r = tid >> 4;          // 0..15
    const int c0 = (tid & 15) * 8;   // 0..120

    float acc[8];
#pragma unroll
    for (int j = 0; j < 8; j++) acc[j] = 0.f;

    for (int d = 0; d < D; d += 4) {
        float4 a4 = *(const float4*)&As[r][d];
#pragma unroll
        for (int dd = 0; dd < 4; dd++) {
            float av = (dd == 0) ? a4.x : (dd == 1) ? a4.y : (dd == 2) ? a4.z : a4.w;
            float4 w0 = *(const float4*)&w[(size_t)(d + dd) * P + c0];
            float4 w1 = *(const float4*)&w[(size_t)(d + dd) * P + c0 + 4];
            acc[0] = fmaf(av, w0.x, acc[0]);
            acc[1] = fmaf(av, w0.y, acc[1]);
            acc[2] = fmaf(av, w0.z, acc[2]);
            acc[3] = fmaf(av, w0.w, acc[3]);
            acc[4] = fmaf(av, w1.x, acc[4]);
            acc[5] = fmaf(av, w1.y, acc[5]);
            acc[6] = fmaf(av, w1.z, acc[6]);
            acc[7] = fmaf(av, w1.w, acc[7]);
        }
    }

    float out[8];
    float nrm = 0.f;
    u16x8 hv;
#pragma unroll
    for (int j = 0; j < 8; j++) {
        out[j] = acc[j] + bias[c0 + j];
        nrm = fmaf(out[j], out[j], nrm);
        hv[j] = f32_to_bf16_rne(out[j]);
    }

    const int gr = row0 + r;
    float* dst;
    unsigned short* hdst;
    if (gr < NTOK) { dst = xproj + (size_t)gr * P; hdst = xh + (size_t)gr * P; }
    else           { dst = cproj + (size_t)(gr - NTOK) * P; hdst = ch + (size_t)(gr - NTOK) * P; }
    float4 o0; o0.x = out[0]; o0.y = out[1]; o0.z = out[2]; o0.w = out[3];
    float4 o1; o1.x = out[4]; o1.y = out[5]; o1.z = out[6]; o1.w = out[7];
    *(float4*)&dst[c0] = o0;
    *(float4*)&dst[c0 + 4] = o1;
    *(u16x8*)&hdst[c0] = hv;

#pragma unroll
    for (int off = 1; off < 16; off <<= 1)
        nrm += __shfl_xor(nrm, off, 16);
    if ((tid & 15) == 0) {
        if (gr < NTOK) xnorm[gr] = nrm;
        else           cnorm[gr - NTOK] = nrm;
    }
}

// ---------------------------------------------------------------------------
// Kernel 2: bf16 MFMA distance filter. Block = 256 thr (4 waves) handles
// 64 tokens x a 1024-code chunk, looping over 16 code-tiles of 64 codes.
// Wave layout: 2x2 waves; each wave computes a 32x32 tile via 2x2 MFMA
// 16x16x32 tiles over 4 k-steps (P=128). Collects candidate codes whose
// approx distance <= running chunk-min + MARGIN (superset of fp32 argmin).
// ---------------------------------------------------------------------------
__global__ __launch_bounds__(256) void filter_kernel(
    const unsigned short* __restrict__ xh, const unsigned short* __restrict__ ch,
    const float* __restrict__ xnorm, const float* __restrict__ cnorm,
    float* __restrict__ chunkmin, int* __restrict__ cand)
{
    __shared__ short sa[64][136];   // tokens x P, pad +8
    __shared__ short sb[64][136];   // codes  x P
    __shared__ float smin[64];
    __shared__ int scnt[64];
    __shared__ int scand[64][CAP];

    const int tid = threadIdx.x;
    const int tok0 = blockIdx.x * 64;
    const int chunk = blockIdx.y;
    const int k0 = chunk * KCHUNK;

    const int wave = tid >> 6;      // 0..3
    const int lane = tid & 63;
    const int quad = lane >> 4;     // 0..3
    const int l15 = lane & 15;
    const int wm = wave >> 1;       // token-half (0/1)
    const int wn = wave & 1;        // code-half (0/1)

    // Stage A tile (64 tokens x 128 bf16) once.
    for (int i = tid; i < 64 * 16; i += 256) {
        int row = i >> 4;
        int c8 = i & 15;
        uint4 v = *(const uint4*)(xh + (size_t)(tok0 + row) * P + c8 * 8);
        *(uint4*)&sa[row][c8 * 8] = v;
    }
    if (tid < 64) { smin[tid] = FLT_BIG; scnt[tid] = 0; }

    // Preload xnorm for this lane's 8 token slots.
    float xnv[2][4];
#pragma unroll
    for (int mi = 0; mi < 2; mi++)
#pragma unroll
        for (int r = 0; r < 4; r++)
            xnv[mi][r] = xnorm[tok0 + wm * 32 + mi * 16 + quad * 4 + r];

    for (int ct = 0; ct < KCHUNK / 64; ct++) {
        const int kt = k0 + ct * 64;
        __syncthreads();   // prior tile fully consumed (and smin/scnt init on ct==0)
        for (int i = tid; i < 64 * 16; i += 256) {
            int row = i >> 4;
            int c8 = i & 15;
            uint4 v = *(const uint4*)(ch + (size_t)(kt + row) * P + c8 * 8);
            *(uint4*)&sb[row][c8 * 8] = v;
        }
        __syncthreads();

        f32x4 acc[2][2];
#pragma unroll
        for (int mi = 0; mi < 2; mi++)
#pragma unroll
            for (int nj = 0; nj < 2; nj++)
                acc[mi][nj] = (f32x4)(0.f);

#pragma unroll
        for (int ks = 0; ks < 4; ks++) {
            const int kf = ks * 32 + quad * 8;
            bf16x8 a0 = *(const bf16x8*)&sa[wm * 32 + l15][kf];
            bf16x8 a1 = *(const bf16x8*)&sa[wm * 32 + 16 + l15][kf];
            bf16x8 b0 = *(const bf16x8*)&sb[wn * 32 + l15][kf];
            bf16x8 b1 = *(const bf16x8*)&sb[wn * 32 + 16 + l15][kf];
            acc[0][0] = __builtin_amdgcn_mfma_f32_16x16x32_bf16(a0, b0, acc[0][0], 0, 0, 0);
            acc[0][1] = __builtin_amdgcn_mfma_f32_16x16x32_bf16(a0, b1, acc[0][1], 0, 0, 0);
            acc[1][0] = __builtin_amdgcn_mfma_f32_16x16x32_bf16(a1, b0, acc[1][0], 0, 0, 0);
            acc[1][1] = __builtin_amdgcn_mfma_f32_16x16x32_bf16(a1, b1, acc[1][1], 0, 0, 0);
        }

        // distances: token = tok0 + wm*32 + mi*16 + quad*4 + r (D-row)
        //            code  = kt  + wn*32 + nj*16 + l15        (D-col)
        float cn0 = cnorm[kt + wn * 32 + l15];
        float cn1 = cnorm[kt + wn * 32 + 16 + l15];
        float d[2][2][4];
        float mn[2][4];
#pragma unroll
        for (int mi = 0; mi < 2; mi++)
#pragma unroll
            for (int r = 0; r < 4; r++) {
                float d0 = (xnv[mi][r] - 2.0f * acc[mi][0][r]) + cn0;
                float d1 = (xnv[mi][r] - 2.0f * acc[mi][1][r]) + cn1;
                d[mi][0][r] = d0;
                d[mi][1][r] = d1;
                mn[mi][r] = fminf(d0, d1);
            }
        // min over the 16 lanes of each row (code dimension)
#pragma unroll
        for (int off = 1; off < 16; off <<= 1) {
#pragma unroll
            for (int mi = 0; mi < 2; mi++)
#pragma unroll
                for (int r = 0; r < 4; r++)
                    mn[mi][r] = fminf(mn[mi][r], __shfl_xor(mn[mi][r], off));
        }
        if (l15 == 0) {
#pragma unroll
            for (int mi = 0; mi < 2; mi++)
#pragma unroll
                for (int r = 0; r < 4; r++) {
                    int tl = wm * 32 + mi * 16 + quad * 4 + r;
                    atomicMin((int*)&smin[tl], __float_as_int(mn[mi][r]));
                }
        }
        __syncthreads();

        // collect candidates within MARGIN of running chunk-min
#pragma unroll
        for (int mi = 0; mi < 2; mi++)
#pragma unroll
            for (int r = 0; r < 4; r++) {
                int tl = wm * 32 + mi * 16 + quad * 4 + r;
                float thr = smin[tl] + MARGIN;
#pragma unroll
                for (int nj = 0; nj < 2; nj++) {
                    if (d[mi][nj][r] <= thr) {
                        int pos = atomicAdd(&scnt[tl], 1);
                        if (pos < CAP)
                            scand[tl][pos] = kt + wn * 32 + nj * 16 + l15;
                    }
                }
            }
    }
    __syncthreads();

    if (tid < 64) {
        int t = tok0 + tid;
        int cnt = scnt[tid];
        if (cnt > CAP) cnt = CAP;
        int* rec = cand + ((size_t)t * NCHUNK + chunk) * (CAP + 1);
        rec[0] = cnt;
        for (int j = 0; j < cnt; j++) rec[1 + j] = scand[tid][j];
        chunkmin[(size_t)t * NCHUNK + chunk] = smin[tid];
    }
}

// ---------------------------------------------------------------------------
// Kernel 3: exact fp32 rescore of candidates. One wave per token.
// Same serial-fma arithmetic/order as the round-1 kernel (matched numpy).
// ---------------------------------------------------------------------------
__global__ __launch_bounds__(256) void rescore_kernel(
    const float* __restrict__ xproj, const float* __restrict__ cproj,
    const float* __restrict__ xnorm, const float* __restrict__ cnorm,
    const float* __restrict__ chunkmin, const int* __restrict__ cand,
    int* __restrict__ fidx)
{
    const int tid = threadIdx.x;
    const int lane = tid & 63;
    const int wave = tid >> 6;
    const int t = blockIdx.x * 4 + wave;

    // global approx min over chunk minima (lanes 0..7 hold the 8 chunk minima)
    float cm = (lane < NCHUNK) ? chunkmin[(size_t)t * NCHUNK + lane] : FLT_BIG;
#pragma unroll
    for (int off = 1; off < 8; off <<= 1)
        cm = fminf(cm, __shfl_xor(cm, off));
    float mg = __shfl(cm, 0);   // wave-relative lane 0 has the min

    const float xn = xnorm[t];
    float bv = FLT_BIG;
    int bi = 0x7fffffff;

    for (int c = 0; c < NCHUNK; c++) {
        if (chunkmin[(size_t)t * NCHUNK + c] > mg + MARGIN) continue;
        const int* rec = cand + ((size_t)t * NCHUNK + c) * (CAP + 1);
        int cnt = rec[0];
        for (int j = 0; j < cnt; j++) {
            if (((c * CAP + j) & 63) != lane) continue;
            int k = rec[1 + j];
            const float* xr = xproj + (size_t)t * P;
            const float* cr = cproj + (size_t)k * P;
            float s = 0.f;
            for (int p = 0; p < P; p += 4) {
                float4 a = *(const float4*)&xr[p];
                float4 b = *(const float4*)&cr[p];
                s = fmaf(a.x, b.x, s);
                s = fmaf(a.y, b.y, s);
                s = fmaf(a.z, b.z, s);
                s = fmaf(a.w, b.w, s);
            }
            float dist = (xn - 2.0f * s) + cnorm[k];
            if (dist < bv || (dist == bv && k < bi)) { bv = dist; bi = k; }
        }
    }

    // wave (val, idx) argmin reduce, tie -> lower index
#pragma unroll
    for (int off = 1; off < 64; off <<= 1) {
        float ov = __shfl_xor(bv, off);
        int oi = __shfl_xor(bi, off);
        if (ov < bv || (ov == bv && oi < bi)) { bv = ov; bi = oi; }
    }
    if (lane == 0) fidx[t] = bi;
}

// ---------------------------------------------------------------------------
// Kernel 4: write the full one-hot rows (fused zero-fill) + gather codebook.
// Block = 256 thr handles 8 tokens. Grid: NTOK/8 = 2048 blocks.
// ---------------------------------------------------------------------------
__global__ __launch_bounds__(256) void output_kernel(
    const int* __restrict__ fidx, const float* __restrict__ cb,
    float* __restrict__ discrete, float* __restrict__ quant)
{
    __shared__ int sidx[8];
    const int tid = threadIdx.x;
    const int tok0 = blockIdx.x * 8;
    if (tid < 8) sidx[tid] = fidx[tok0 + tid];
    __syncthreads();

    // one-hot rows: 8 tokens x 2048 float4 (native vec type for nontemporal)
    for (int i = tid; i < 8 * (K / 4); i += 256) {
        int tl = i >> 11;
        int f4 = i & 2047;
        int id = sidx[tl];
        f32x4 v = (f32x4)(0.f);
        if (f4 == (id >> 2)) v[id & 3] = 1.f;
        __builtin_nontemporal_store(v, (f32x4*)(discrete + (size_t)(tok0 + tl) * K + f4 * 4));
    }

    // quantized rows: 8 tokens x 64 float4
    for (int i = tid; i < 8 * (D / 4); i += 256) {
        int tl = i >> 6;
        int c4 = i & 63;
        float4 v = ((const float4*)(cb + (size_t)sidx[tl] * D))[c4];
        ((float4*)(quant + (size_t)(tok0 + tl) * D))[c4] = v;
    }
}

// ---------------------------------------------------------------------------
extern "C" void kernel_launch(void* const* d_in, const int* in_sizes, int n_in,
                              void* d_out, int out_size, void* d_ws, size_t ws_size,
                              hipStream_t stream) {
    const float* x    = (const float*)d_in[0];   // [16,1024,256]
    const float* cb   = (const float*)d_in[1];   // [8192,256]
    const float* w    = (const float*)d_in[2];   // [256,128]
    const float* bias = (const float*)d_in[3];   // [128]

    float* out = (float*)d_out;
    float* discrete = out;                               // [16384, 8192]
    float* quant = out + (size_t)NTOK * K;               // [16384, 256]

    char* ws = (char*)d_ws;
    size_t off = 0;
    float* xproj = (float*)(ws + off); off += (size_t)NTOK * P * 4;
    float* cproj = (float*)(ws + off); off += (size_t)K * P * 4;
    float* xnorm = (float*)(ws + off); off += (size_t)NTOK * 4;
    float* cnorm = (float*)(ws + off); off += (size_t)K * 4;
    unsigned short* xh = (unsigned short*)(ws + off); off += (size_t)NTOK * P * 2;
    unsigned short* ch = (unsigned short*)(ws + off); off += (size_t)K * P * 2;
    float* chunkmin = (float*)(ws + off); off += (size_t)NTOK * NCHUNK * 4;
    int* cand = (int*)(ws + off); off += (size_t)NTOK * NCHUNK * (CAP + 1) * 4;
    int* fidx = (int*)(ws + off); off += (size_t)NTOK * 4;

    proj_kernel<<<dim3(NROWS / 16), dim3(256), 0, stream>>>(
        x, cb, w, bias, xproj, cproj, xnorm, cnorm, xh, ch);

    filter_kernel<<<dim3(NTOK / 64, NCHUNK), dim3(256), 0, stream>>>(
        xh, ch, xnorm, cnorm, chunkmin, cand);

    rescore_kernel<<<dim3(NTOK / 4), dim3(256), 0, stream>>>(
        xproj, cproj, xnorm, cnorm, chunkmin, cand, fidx);

    output_kernel<<<dim3(NTOK / 8), dim3(256), 0, stream>>>(
        fidx, cb, discrete, quant);
}